// Round 14
// baseline (357.402 us; speedup 1.0000x reference)
//
#include <hip/hip_runtime.h>
#include <hip/hip_bf16.h>
#include <math.h>

// MambaBlock: B=4, L=1024, D_MODEL=512, D_INNER=1024, D_STATE=16, D_CONV=4, DT_RANK=32
// fp32 in/out. bf16 MFMA for gemm1/gemm6; fp32 SIMT split-K for gemm3;
// delta (K=32) as SIMT dot+softplus. Scan: fused 3-phase, one block per (b,d),
// with phase-A products (exp2 decay + dBu) register-cached for phase C.
#define B_   4
#define L_   1024
#define DM   512
#define DI   1024
#define NS   16
#define XDC  64      // DT_RANK + 2*D_STATE
#define BL   4096    // B_*L_
#define G_   16      // scan segments
#define SEG  64      // L_/G_
#define KS   4       // gemm3 split-K factor
#define LOG2E 1.44269504f

typedef short bfrag __attribute__((ext_vector_type(8)));   // 8 bf16
typedef float ffrag __attribute__((ext_vector_type(4)));   // 4 fp32 acc

__device__ __forceinline__ ushort f2bf(float v) {
    __hip_bfloat16 h = __float2bfloat16(v);
    return *(ushort*)&h;
}

// All fp32->bf16 weight/input casts in ONE launch.
__global__ __launch_bounds__(256) void cast_all(const float* __restrict__ x,
        const float* __restrict__ ipw, const float* __restrict__ opw,
        ushort* __restrict__ xB, ushort* __restrict__ wInB,
        ushort* __restrict__ wOutB)
{
    int i = blockIdx.x * 256 + threadIdx.x;
    const float4* src; ushort4* dst; int idx;
    if (i < 524288)      { src = (const float4*)x;   dst = (ushort4*)xB;    idx = i; }
    else if (i < 786432) { src = (const float4*)ipw; dst = (ushort4*)wInB;  idx = i - 524288; }
    else if (i < 917504) { src = (const float4*)opw; dst = (ushort4*)wOutB; idx = i - 786432; }
    else return;
    float4 v = src[idx];
    ushort4 o;
    o.x = f2bf(v.x); o.y = f2bf(v.y); o.z = f2bf(v.z); o.w = f2bf(v.w);
    dst[idx] = o;
}

// MFMA bf16 TN GEMM: C[M,N] = A[M,K] * B[N,K]^T, fp32 out.
// EPI: 0 none; 2 C += resid[m*ldc+n]
template<int EPI>
__global__ __launch_bounds__(256) void gemm_mfma(const ushort* __restrict__ A,
        const ushort* __restrict__ B, float* __restrict__ C,
        int K, int ldc, const float* __restrict__ resid)
{
    __shared__ ushort As[128][40];
    __shared__ ushort Bs[128][40];
    const int tid = threadIdx.x;
    const int lane = tid & 63, wave = tid >> 6;
    const int wm = (wave & 1) * 64, wn = (wave >> 1) * 64;
    const int l15 = lane & 15, quad = lane >> 4;
    const int m0 = blockIdx.y * 128, n0 = blockIdx.x * 128;

    ffrag acc[4][4] = {};

    for (int k0 = 0; k0 < K; k0 += 32) {
        #pragma unroll
        for (int i = 0; i < 2; i++) {
            int chunk = tid + i * 256;
            int row = chunk >> 2, kk8 = (chunk & 3) * 8;
            *(uint4*)&As[row][kk8] = *(const uint4*)&A[(size_t)(m0 + row) * K + k0 + kk8];
            *(uint4*)&Bs[row][kk8] = *(const uint4*)&B[(size_t)(n0 + row) * K + k0 + kk8];
        }
        __syncthreads();
        bfrag af[4], bfv[4];
        #pragma unroll
        for (int i = 0; i < 4; i++) {
            af[i]  = *(const bfrag*)&As[wm + i * 16 + l15][quad * 8];
            bfv[i] = *(const bfrag*)&Bs[wn + i * 16 + l15][quad * 8];
        }
        #pragma unroll
        for (int i = 0; i < 4; i++)
            #pragma unroll
            for (int j = 0; j < 4; j++)
                acc[i][j] = __builtin_amdgcn_mfma_f32_16x16x32_bf16(af[i], bfv[j], acc[i][j], 0, 0, 0);
        __syncthreads();
    }

    #pragma unroll
    for (int i = 0; i < 4; i++) {
        #pragma unroll
        for (int j = 0; j < 4; j++) {
            int n = n0 + wn + j * 16 + l15;
            #pragma unroll
            for (int r = 0; r < 4; r++) {
                int m = m0 + wm + i * 16 + quad * 4 + r;
                float v = acc[i][j][r];
                if (EPI == 2) v += resid[(size_t)m * ldc + n];
                C[(size_t)m * ldc + n] = v;
            }
        }
    }
}

// gemm3 split-K: part[ks][m][n] over K-chunk ks. A = uT [DI][BL], W = x_proj_w.
__global__ __launch_bounds__(256) void gemm3_splitk(const float* __restrict__ uT,
        const float* __restrict__ xw, float* __restrict__ part)
{
    __shared__ float As[16][33];
    __shared__ float Ws[16][68];
    const int tid = threadIdx.x;
    const int tx = tid & 15, ty = tid >> 4;
    const int ks = blockIdx.x, m0 = blockIdx.y * 32;
    const int kbase = ks * (DI / KS);
    float acc[2][4] = {};

    for (int k0 = 0; k0 < DI / KS; k0 += 16) {
        if (tid < 128) {
            int k = tid >> 3, m4 = (tid & 7) * 4;
            const float4 v = *(const float4*)&uT[(size_t)(kbase + k0 + k) * BL + m0 + m4];
            As[k][m4 + 0] = v.x; As[k][m4 + 1] = v.y;
            As[k][m4 + 2] = v.z; As[k][m4 + 3] = v.w;
        }
        {
            int r = tid >> 2, c4 = (tid & 3) * 4;
            const float4 v = *(const float4*)&xw[(size_t)r * DI + kbase + k0 + c4];
            Ws[c4 + 0][r] = v.x; Ws[c4 + 1][r] = v.y;
            Ws[c4 + 2][r] = v.z; Ws[c4 + 3][r] = v.w;
        }
        __syncthreads();
        #pragma unroll
        for (int kk = 0; kk < 16; kk++) {
            float a[2], b[4];
            a[0] = As[kk][ty * 2 + 0];
            a[1] = As[kk][ty * 2 + 1];
            #pragma unroll
            for (int j = 0; j < 4; j++) b[j] = Ws[kk][tx * 4 + j];
            #pragma unroll
            for (int i = 0; i < 2; i++)
                #pragma unroll
                for (int j = 0; j < 4; j++)
                    acc[i][j] = fmaf(a[i], b[j], acc[i][j]);
        }
        __syncthreads();
    }

    float* pp = part + (size_t)ks * BL * XDC;
    #pragma unroll
    for (int i = 0; i < 2; i++) {
        int m = m0 + ty * 2 + i;
        *(float4*)&pp[(size_t)m * XDC + tx * 4] =
            make_float4(acc[i][0], acc[i][1], acc[i][2], acc[i][3]);
    }
}

// reduce KS partials; emit fp32 dt rows (cols 0..31) and 16-tiled
// Bsc/Csc[b][l/16][n][l%16] (cols 32..47 / 48..63).
__global__ __launch_bounds__(256) void gemm3_reduce(const float* __restrict__ part,
        float* __restrict__ dtF, float* __restrict__ Bsc, float* __restrict__ Csc)
{
    int i = blockIdx.x * 256 + threadIdx.x;     // over BL*XDC/4 = 65536
    const float4* p0 = (const float4*)part;
    float4 a = p0[i];
    #pragma unroll
    for (int s = 1; s < KS; s++) {
        float4 b = p0[i + (size_t)s * BL * XDC / 4];
        a.x += b.x; a.y += b.y; a.z += b.z; a.w += b.w;
    }
    int c4 = i & 15;
    int m = i >> 4;
    if (c4 < 8) {
        ((float4*)dtF)[m * 8 + c4] = a;
    } else {
        int b = m >> 10, l = m & (L_ - 1);
        int nb = (c4 < 12) ? (c4 - 8) * 4 : (c4 - 12) * 4;
        float* dst = (c4 < 12) ? Bsc : Csc;
        size_t base = ((size_t)((b * (L_ / 16) + (l >> 4)) * NS + nb) << 4) + (l & 15);
        dst[base + 0 * 16] = a.x;
        dst[base + 1 * 16] = a.y;
        dst[base + 2 * 16] = a.z;
        dst[base + 3 * 16] = a.w;
    }
}

// deltaT[d][bl] = softplus(dt[bl] . dtw[d] + bias[d]), K=32 fp32.
__global__ __launch_bounds__(256) void delta_kernel(const float* __restrict__ dtF,
        const float* __restrict__ dtw, const float* __restrict__ bias,
        float* __restrict__ deltaT)
{
    int idx = blockIdx.x * 256 + threadIdx.x;
    int bl = idx & (BL - 1);
    int dg = idx >> 12;
    float a[32];
    const float4* ap = (const float4*)(dtF + (size_t)bl * 32);
    #pragma unroll
    for (int i = 0; i < 8; i++) *(float4*)&a[i * 4] = ap[i];
    #pragma unroll
    for (int r = 0; r < 4; r++) {
        int d = dg * 4 + r;
        const float* w = dtw + (size_t)d * 32;
        float acc = bias[d];
        #pragma unroll
        for (int k = 0; k < 32; k++) acc = fmaf(a[k], w[k], acc);
        acc = (acc > 20.f) ? acc : log1pf(__expf(acc));
        deltaT[(size_t)d * BL + bl] = acc;
    }
}

// depthwise causal conv (k=4) + bias + SiLU, channel-major, 4 outputs/thread.
__global__ __launch_bounds__(256) void conv_silu(const float* __restrict__ xzT,
        const float* __restrict__ cw, const float* __restrict__ cb,
        float* __restrict__ uT)
{
    int i = blockIdx.x * 256 + threadIdx.x;
    int d  = i >> 10;
    int q  = i & 1023;
    int bl = q * 4;
    int l  = bl & (L_ - 1);
    const float* row = xzT + (size_t)d * BL;
    float4 cur = *(const float4*)&row[bl];
    float4 prev = make_float4(0.f, 0.f, 0.f, 0.f);
    if (l != 0) prev = *(const float4*)&row[bl - 4];
    float v[7] = { prev.y, prev.z, prev.w, cur.x, cur.y, cur.z, cur.w };
    float w0 = cw[d * 4 + 0], w1 = cw[d * 4 + 1], w2 = cw[d * 4 + 2], w3 = cw[d * 4 + 3];
    float bias = cb[d];
    float4 o;
    o.x = bias + w0 * v[0] + w1 * v[1] + w2 * v[2] + w3 * v[3];
    o.y = bias + w0 * v[1] + w1 * v[2] + w2 * v[3] + w3 * v[4];
    o.z = bias + w0 * v[2] + w1 * v[3] + w2 * v[4] + w3 * v[5];
    o.w = bias + w0 * v[3] + w1 * v[4] + w2 * v[5] + w3 * v[6];
    o.x = o.x / (1.f + __expf(-o.x));
    o.y = o.y / (1.f + __expf(-o.y));
    o.z = o.z / (1.f + __expf(-o.z));
    o.w = o.w / (1.f + __expf(-o.w));
    *(float4*)&uT[(size_t)d * BL + bl] = o;
}

// ---- fused chunk-decomposed selective scan, register-cached coefficients ----
// One block per (b,d): 16 segments x 16 n-lanes. Phase A computes and CACHES
// dvE (exp2 decay) and Bq (dBu) for all 64 owned timesteps (128 VGPRs, static
// indexing); phase C runs the recurrence purely from registers (only C-tile,
// gate loads). __launch_bounds__(256,3) caps VGPR at ~170 (3 waves/SIMD).
__global__ __launch_bounds__(256, 3) void scan_fused(const float* __restrict__ deltaT,
        const float* __restrict__ uT, const float* __restrict__ Bsc,
        const float* __restrict__ Csc, const float* __restrict__ xzT,
        const float* __restrict__ A_log, const float* __restrict__ Dp,
        float* __restrict__ yT)
{
    __shared__ float hend_s[G_][NS + 1];
    __shared__ float h0_s[G_][NS + 1];
    __shared__ float sdv_s[G_];

    const int tid = threadIdx.x;
    const int n = tid & 15;
    const int seg = tid >> 4;          // 0..15
    const int bd = blockIdx.x;         // b*DI + d
    const int d = bd & (DI - 1);
    const int b = bd >> 10;

    const float Acoef = -__expf(A_log[d * NS + n]) * LOG2E;
    const float Dd = Dp[d];

    const size_t base_t  = (size_t)d * BL + b * L_ + seg * SEG;
    const size_t base_z  = (size_t)(DI + d) * BL + b * L_ + seg * SEG;
    const size_t base_bc = ((size_t)((b * (L_ / 16) + seg * 4) * NS + n)) << 4;

    float dvE[4][16], Bq[4][16];

    // ---- Phase A: local scan (h0=0); cache dvE/Bq ----
    float h = 0.f, sdv = 0.f;
    #pragma unroll
    for (int c = 0; c < 4; c++) {
        const int l0 = c * 16;
        const float4* dp = (const float4*)(deltaT + base_t + l0);
        const float4* up = (const float4*)(uT + base_t + l0);
        const float4* bp = (const float4*)(Bsc + base_bc + (size_t)c * (NS * 16));
        #pragma unroll
        for (int i = 0; i < 4; i++) {
            float4 d4 = dp[i], u4 = up[i], b4 = bp[i];
            float dd[4] = { d4.x, d4.y, d4.z, d4.w };
            float uu[4] = { u4.x, u4.y, u4.z, u4.w };
            float bb[4] = { b4.x, b4.y, b4.z, b4.w };
            #pragma unroll
            for (int k = 0; k < 4; k++) {
                const int j = i * 4 + k;
                sdv += dd[k];
                Bq[c][j]  = bb[k] * (dd[k] * uu[k]);
                dvE[c][j] = exp2f(dd[k] * Acoef);
            }
        }
        #pragma unroll
        for (int j = 0; j < 16; j++)
            h = fmaf(dvE[c][j], h, Bq[c][j]);
    }
    hend_s[seg][n] = h;
    if (n == 0) sdv_s[seg] = sdv;
    __syncthreads();

    // ---- Phase B: serial combine -> per-segment h0 ----
    if (seg == 0) {
        float H = 0.f;
        #pragma unroll
        for (int s = 0; s < G_; s++) {
            h0_s[s][n] = H;
            H = hend_s[s][n] + exp2f(Acoef * sdv_s[s]) * H;
        }
    }
    __syncthreads();

    // ---- Phase C: recurrence from cached coefficients ----
    h = h0_s[seg][n];
    #pragma unroll
    for (int c = 0; c < 4; c++) {
        const int l0 = c * 16;
        float ug = uT [base_t + l0 + n];
        float zg = xzT[base_z + l0 + n];
        float Cv[16];
        const float4* cp = (const float4*)(Csc + base_bc + (size_t)c * (NS * 16));
        #pragma unroll
        for (int i = 0; i < 4; i++) *(float4*)&Cv[i * 4] = cp[i];

        float p[16];
        #pragma unroll
        for (int j = 0; j < 16; j++) {
            h = fmaf(dvE[c][j], h, Bq[c][j]);
            p[j] = h * Cv[j];
        }

        // halving butterfly: final owner of timestep j is lane n=j.
        float q8[8];
        #pragma unroll
        for (int k = 0; k < 8; k++) {
            float tt = (n & 8) ? p[k] : p[k + 8];
            float rr = __shfl_xor(tt, 8);
            q8[k] = ((n & 8) ? p[k + 8] : p[k]) + rr;
        }
        float q4[4];
        #pragma unroll
        for (int k = 0; k < 4; k++) {
            float tt = (n & 4) ? q8[k] : q8[k + 4];
            float rr = __shfl_xor(tt, 4);
            q4[k] = ((n & 4) ? q8[k + 4] : q8[k]) + rr;
        }
        float q2[2];
        #pragma unroll
        for (int k = 0; k < 2; k++) {
            float tt = (n & 2) ? q4[k] : q4[k + 2];
            float rr = __shfl_xor(tt, 2);
            q2[k] = ((n & 2) ? q4[k + 2] : q4[k]) + rr;
        }
        float tt = (n & 1) ? q2[0] : q2[1];
        float rr = __shfl_xor(tt, 1);
        float S = ((n & 1) ? q2[1] : q2[0]) + rr;

        float v = S + ug * Dd;
        v *= zg / (1.f + __expf(-zg));
        yT[base_t + l0 + n] = v;
    }
}

// yT fp32 [DI][BL] -> yB bf16 [BL][DI], 64x64 LDS tiles.
__global__ __launch_bounds__(256) void transpose_cast(const float* __restrict__ yT,
        ushort* __restrict__ yB)
{
    __shared__ float t[64][65];
    const int bl0 = blockIdx.x * 64, d0 = blockIdx.y * 64;
    const int tid = threadIdx.x;
    #pragma unroll
    for (int i = 0; i < 4; i++) {
        int chunk = tid + i * 256;
        int dr = chunk >> 4, c4 = (chunk & 15) * 4;
        const float4 v = *(const float4*)&yT[(size_t)(d0 + dr) * BL + bl0 + c4];
        t[dr][c4 + 0] = v.x; t[dr][c4 + 1] = v.y;
        t[dr][c4 + 2] = v.z; t[dr][c4 + 3] = v.w;
    }
    __syncthreads();
    #pragma unroll
    for (int i = 0; i < 4; i++) {
        int chunk = tid + i * 256;
        int br = chunk >> 4, dc4 = (chunk & 15) * 4;
        ushort4 o;
        o.x = f2bf(t[dc4 + 0][br]); o.y = f2bf(t[dc4 + 1][br]);
        o.z = f2bf(t[dc4 + 2][br]); o.w = f2bf(t[dc4 + 3][br]);
        *(ushort4*)&yB[(size_t)(bl0 + br) * DI + d0 + dc4] = o;
    }
}

// LayerNorm over last dim (512), one block per row, fp32 out.
__global__ __launch_bounds__(256) void ln_kernel(const float* __restrict__ r,
        const float* __restrict__ lnw, const float* __restrict__ lnb,
        float* __restrict__ out)
{
    int row = blockIdx.x;
    const float* rr = r + (size_t)row * DM;
    float v0 = rr[threadIdx.x], v1 = rr[threadIdx.x + 256];
    float s = v0 + v1, s2 = v0 * v0 + v1 * v1;
    #pragma unroll
    for (int off = 32; off > 0; off >>= 1) {
        s  += __shfl_down(s, off);
        s2 += __shfl_down(s2, off);
    }
    __shared__ float ls[4], ls2[4];
    __shared__ float mu_s, rstd_s;
    int wid = threadIdx.x >> 6, lane = threadIdx.x & 63;
    if (lane == 0) { ls[wid] = s; ls2[wid] = s2; }
    __syncthreads();
    if (threadIdx.x == 0) {
        float S = ls[0] + ls[1] + ls[2] + ls[3];
        float S2 = ls2[0] + ls2[1] + ls2[2] + ls2[3];
        float mu = S * (1.f / DM);
        float var = S2 * (1.f / DM) - mu * mu;
        mu_s = mu;
        rstd_s = rsqrtf(var + 1e-5f);
    }
    __syncthreads();
    float mu = mu_s, rstd = rstd_s;
    out[(size_t)row * DM + threadIdx.x] =
        (v0 - mu) * rstd * lnw[threadIdx.x] + lnb[threadIdx.x];
    out[(size_t)row * DM + threadIdx.x + 256] =
        (v1 - mu) * rstd * lnw[threadIdx.x + 256] + lnb[threadIdx.x + 256];
}

extern "C" void kernel_launch(void* const* d_in, const int* in_sizes, int n_in,
                              void* d_out, int out_size, void* d_ws, size_t ws_size,
                              hipStream_t stream)
{
    const float* x         = (const float*)d_in[0];
    const float* in_proj_w = (const float*)d_in[1];
    const float* conv_w    = (const float*)d_in[2];
    const float* conv_b    = (const float*)d_in[3];
    const float* x_proj_w  = (const float*)d_in[4];
    const float* dt_proj_w = (const float*)d_in[5];
    const float* dt_proj_b = (const float*)d_in[6];
    const float* A_log     = (const float*)d_in[7];
    const float* Dvec      = (const float*)d_in[8];
    const float* out_proj_w= (const float*)d_in[9];
    const float* ln_w      = (const float*)d_in[10];
    const float* ln_b      = (const float*)d_in[11];
    float* out = (float*)d_out;

    // fp32 regions (floats). Total ~89.5 MB.
    float* ws     = (float*)d_ws;
    float* xzT    = ws;                                  // 2048x4096 (32 MB)
    float* uT     = xzT    + (size_t)2048 * BL;          // 1024x4096 (16 MB)
    float* deltaT = uT     + (size_t)DI * BL;            // 1024x4096 (16 MB)
    float* yT     = deltaT + (size_t)DI * BL;            // 1024x4096 (16 MB)
    float* r      = yT     + (size_t)DI * BL;            // 4096x512  (8 MB)
    float* Bsc    = r      + (size_t)BL * DM;            // 65536 fl (0.25 MB)
    float* Csc    = Bsc    + (size_t)B_ * NS * L_;       // 0.25 MB
    ushort* wOutB = (ushort*)(Csc + (size_t)B_ * NS * L_); // 512x1024 bf16 (1 MB)
    // aliases over time-dead regions (strictly sequential reuse):
    ushort* xB    = (ushort*)yT;                          // x bf16, dead after gemm1
    float*  xdblp = yT;                                   // gemm3 partials (4 MB), after gemm1
    ushort* wInB  = (ushort*)deltaT;                      // in_proj bf16, dead before delta_kernel writes deltaT
    ushort* yB    = (ushort*)deltaT;                      // y bf16, written after scan (deltaT dead)
    float*  dtF   = r;                                    // 4096x32 fp32 (512 KB), r dead until gemm6b

    dim3 blk(256);

    // 0) bf16 casts (x, in_proj_w, out_proj_w) in one launch
    cast_all<<<(917504 + 255) / 256, blk, 0, stream>>>(
        x, in_proj_w, out_proj_w, xB, wInB, wOutB);

    // 1) xzT[e][bl] = in_proj_w @ x^T : M=2048, N=4096, K=512 (MFMA)
    gemm_mfma<0><<<dim3(BL / 128, 2048 / 128), blk, 0, stream>>>(
        wInB, xB, xzT, DM, BL, nullptr);

    // 2) uT = silu(causal_conv(xsT) + cb)
    conv_silu<<<(DI * BL / 4) / 256, blk, 0, stream>>>(xzT, conv_w, conv_b, uT);

    // 3) x_dbl: split-K partials + reduce (emits fp32 dtF + tiled Bsc/Csc)
    gemm3_splitk<<<dim3(KS, BL / 32), blk, 0, stream>>>(uT, x_proj_w, xdblp);
    gemm3_reduce<<<(BL * XDC / 4) / 256, blk, 0, stream>>>(xdblp, dtF, Bsc, Csc);

    // 4) deltaT = softplus(dt @ dtw^T + b) as SIMT dot kernel (K=32, fp32)
    delta_kernel<<<(DI / 4 * BL) / 256, blk, 0, stream>>>(
        dtF, dt_proj_w, dt_proj_b, deltaT);

    // 5) fused selective scan + gate (one block per (b,d), cached coefficients)
    scan_fused<<<B_ * DI, blk, 0, stream>>>(
        deltaT, uT, Bsc, Csc, xzT, A_log, Dvec, yT);

    // 6a) yT -> yB (bf16, [bl][d])
    transpose_cast<<<dim3(BL / 64, DI / 64), blk, 0, stream>>>(yT, yB);

    // 6b) r[bl][dm] = y @ out_proj_w^T + x : M=4096, N=512, K=1024 (MFMA, resid epi)
    gemm_mfma<2><<<dim3(DM / 128, BL / 128), blk, 0, stream>>>(
        yB, wOutB, r, DI, DM, x);

    // 7) LayerNorm -> fp32 out
    ln_kernel<<<BL, blk, 0, stream>>>(r, ln_w, ln_b, out);
}

// Round 15
// 271.448 us; speedup vs baseline: 1.3166x; 1.3166x over previous
//
#include <hip/hip_runtime.h>
#include <hip/hip_bf16.h>
#include <math.h>

// MambaBlock: B=4, L=1024, D_MODEL=512, D_INNER=1024, D_STATE=16, D_CONV=4, DT_RANK=32
// fp32 in/out. bf16 MFMA for gemm1/gemm6; fp32 SIMT split-K for gemm3;
// delta (K=32) as SIMT dot+softplus reading xdbl directly.
// Scan: R10-proven fused 3-phase kernel (xdbl scalar B/C loads, 76.7 us).
#define B_   4
#define L_   1024
#define DM   512
#define DI   1024
#define NS   16
#define XDC  64      // DT_RANK + 2*D_STATE
#define BL   4096    // B_*L_
#define G_   16      // scan segments
#define SEG  64      // L_/G_
#define KS   4       // gemm3 split-K factor

typedef short bfrag __attribute__((ext_vector_type(8)));   // 8 bf16
typedef float ffrag __attribute__((ext_vector_type(4)));   // 4 fp32 acc

__device__ __forceinline__ ushort f2bf(float v) {
    __hip_bfloat16 h = __float2bfloat16(v);
    return *(ushort*)&h;
}

// All fp32->bf16 weight/input casts in ONE launch.
__global__ __launch_bounds__(256) void cast_all(const float* __restrict__ x,
        const float* __restrict__ ipw, const float* __restrict__ opw,
        ushort* __restrict__ xB, ushort* __restrict__ wInB,
        ushort* __restrict__ wOutB)
{
    int i = blockIdx.x * 256 + threadIdx.x;
    const float4* src; ushort4* dst; int idx;
    if (i < 524288)      { src = (const float4*)x;   dst = (ushort4*)xB;    idx = i; }
    else if (i < 786432) { src = (const float4*)ipw; dst = (ushort4*)wInB;  idx = i - 524288; }
    else if (i < 917504) { src = (const float4*)opw; dst = (ushort4*)wOutB; idx = i - 786432; }
    else return;
    float4 v = src[idx];
    ushort4 o;
    o.x = f2bf(v.x); o.y = f2bf(v.y); o.z = f2bf(v.z); o.w = f2bf(v.w);
    dst[idx] = o;
}

// MFMA bf16 TN GEMM: C[M,N] = A[M,K] * B[N,K]^T, fp32 out.
// EPI: 0 none; 2 C += resid[m*ldc+n]
template<int EPI>
__global__ __launch_bounds__(256) void gemm_mfma(const ushort* __restrict__ A,
        const ushort* __restrict__ B, float* __restrict__ C,
        int K, int ldc, const float* __restrict__ resid)
{
    __shared__ ushort As[128][40];
    __shared__ ushort Bs[128][40];
    const int tid = threadIdx.x;
    const int lane = tid & 63, wave = tid >> 6;
    const int wm = (wave & 1) * 64, wn = (wave >> 1) * 64;
    const int l15 = lane & 15, quad = lane >> 4;
    const int m0 = blockIdx.y * 128, n0 = blockIdx.x * 128;

    ffrag acc[4][4] = {};

    for (int k0 = 0; k0 < K; k0 += 32) {
        #pragma unroll
        for (int i = 0; i < 2; i++) {
            int chunk = tid + i * 256;
            int row = chunk >> 2, kk8 = (chunk & 3) * 8;
            *(uint4*)&As[row][kk8] = *(const uint4*)&A[(size_t)(m0 + row) * K + k0 + kk8];
            *(uint4*)&Bs[row][kk8] = *(const uint4*)&B[(size_t)(n0 + row) * K + k0 + kk8];
        }
        __syncthreads();
        bfrag af[4], bfv[4];
        #pragma unroll
        for (int i = 0; i < 4; i++) {
            af[i]  = *(const bfrag*)&As[wm + i * 16 + l15][quad * 8];
            bfv[i] = *(const bfrag*)&Bs[wn + i * 16 + l15][quad * 8];
        }
        #pragma unroll
        for (int i = 0; i < 4; i++)
            #pragma unroll
            for (int j = 0; j < 4; j++)
                acc[i][j] = __builtin_amdgcn_mfma_f32_16x16x32_bf16(af[i], bfv[j], acc[i][j], 0, 0, 0);
        __syncthreads();
    }

    #pragma unroll
    for (int i = 0; i < 4; i++) {
        #pragma unroll
        for (int j = 0; j < 4; j++) {
            int n = n0 + wn + j * 16 + l15;
            #pragma unroll
            for (int r = 0; r < 4; r++) {
                int m = m0 + wm + i * 16 + quad * 4 + r;
                float v = acc[i][j][r];
                if (EPI == 2) v += resid[(size_t)m * ldc + n];
                C[(size_t)m * ldc + n] = v;
            }
        }
    }
}

// gemm3 split-K: part[ks][m][n] over K-chunk ks. A = uT [DI][BL], W = x_proj_w.
__global__ __launch_bounds__(256) void gemm3_splitk(const float* __restrict__ uT,
        const float* __restrict__ xw, float* __restrict__ part)
{
    __shared__ float As[16][33];
    __shared__ float Ws[16][68];
    const int tid = threadIdx.x;
    const int tx = tid & 15, ty = tid >> 4;
    const int ks = blockIdx.x, m0 = blockIdx.y * 32;
    const int kbase = ks * (DI / KS);
    float acc[2][4] = {};

    for (int k0 = 0; k0 < DI / KS; k0 += 16) {
        if (tid < 128) {
            int k = tid >> 3, m4 = (tid & 7) * 4;
            const float4 v = *(const float4*)&uT[(size_t)(kbase + k0 + k) * BL + m0 + m4];
            As[k][m4 + 0] = v.x; As[k][m4 + 1] = v.y;
            As[k][m4 + 2] = v.z; As[k][m4 + 3] = v.w;
        }
        {
            int r = tid >> 2, c4 = (tid & 3) * 4;
            const float4 v = *(const float4*)&xw[(size_t)r * DI + kbase + k0 + c4];
            Ws[c4 + 0][r] = v.x; Ws[c4 + 1][r] = v.y;
            Ws[c4 + 2][r] = v.z; Ws[c4 + 3][r] = v.w;
        }
        __syncthreads();
        #pragma unroll
        for (int kk = 0; kk < 16; kk++) {
            float a[2], b[4];
            a[0] = As[kk][ty * 2 + 0];
            a[1] = As[kk][ty * 2 + 1];
            #pragma unroll
            for (int j = 0; j < 4; j++) b[j] = Ws[kk][tx * 4 + j];
            #pragma unroll
            for (int i = 0; i < 2; i++)
                #pragma unroll
                for (int j = 0; j < 4; j++)
                    acc[i][j] = fmaf(a[i], b[j], acc[i][j]);
        }
        __syncthreads();
    }

    float* pp = part + (size_t)ks * BL * XDC;
    #pragma unroll
    for (int i = 0; i < 2; i++) {
        int m = m0 + ty * 2 + i;
        *(float4*)&pp[(size_t)m * XDC + tx * 4] =
            make_float4(acc[i][0], acc[i][1], acc[i][2], acc[i][3]);
    }
}

// reduce KS partials -> xdbl [BL][64]
__global__ __launch_bounds__(256) void gemm3_reduce(const float* __restrict__ part,
        float* __restrict__ xdbl)
{
    int i = blockIdx.x * 256 + threadIdx.x;     // over BL*XDC/4
    const float4* p0 = (const float4*)part;
    float4 a = p0[i];
    #pragma unroll
    for (int s = 1; s < KS; s++) {
        float4 b = p0[i + (size_t)s * BL * XDC / 4];
        a.x += b.x; a.y += b.y; a.z += b.z; a.w += b.w;
    }
    ((float4*)xdbl)[i] = a;
}

// deltaT[d][bl] = softplus(dt[bl] . dtw[d] + bias[d]), K=32 fp32.
// dt row = first 32 cols of xdbl[bl] (lda 64). One thread -> 4 d's x 1 bl.
__global__ __launch_bounds__(256) void delta_kernel(const float* __restrict__ xdbl,
        const float* __restrict__ dtw, const float* __restrict__ bias,
        float* __restrict__ deltaT)
{
    int idx = blockIdx.x * 256 + threadIdx.x;   // DI/4 * BL = 1M threads
    int bl = idx & (BL - 1);
    int dg = idx >> 12;                          // 0..255 -> d = dg*4+r
    float a[32];
    const float4* ap = (const float4*)(xdbl + (size_t)bl * XDC);
    #pragma unroll
    for (int i = 0; i < 8; i++) *(float4*)&a[i * 4] = ap[i];
    #pragma unroll
    for (int r = 0; r < 4; r++) {
        int d = dg * 4 + r;
        const float* w = dtw + (size_t)d * 32;
        float acc = bias[d];
        #pragma unroll
        for (int k = 0; k < 32; k++) acc = fmaf(a[k], w[k], acc);
        acc = (acc > 20.f) ? acc : log1pf(__expf(acc));
        deltaT[(size_t)d * BL + bl] = acc;
    }
}

// depthwise causal conv (k=4) + bias + SiLU, channel-major, 4 outputs/thread.
__global__ __launch_bounds__(256) void conv_silu(const float* __restrict__ xzT,
        const float* __restrict__ cw, const float* __restrict__ cb,
        float* __restrict__ uT)
{
    int i = blockIdx.x * 256 + threadIdx.x;
    int d  = i >> 10;
    int q  = i & 1023;
    int bl = q * 4;
    int l  = bl & (L_ - 1);
    const float* row = xzT + (size_t)d * BL;
    float4 cur = *(const float4*)&row[bl];
    float4 prev = make_float4(0.f, 0.f, 0.f, 0.f);
    if (l != 0) prev = *(const float4*)&row[bl - 4];
    float v[7] = { prev.y, prev.z, prev.w, cur.x, cur.y, cur.z, cur.w };
    float w0 = cw[d * 4 + 0], w1 = cw[d * 4 + 1], w2 = cw[d * 4 + 2], w3 = cw[d * 4 + 3];
    float bias = cb[d];
    float4 o;
    o.x = bias + w0 * v[0] + w1 * v[1] + w2 * v[2] + w3 * v[3];
    o.y = bias + w0 * v[1] + w1 * v[2] + w2 * v[3] + w3 * v[4];
    o.z = bias + w0 * v[2] + w1 * v[3] + w2 * v[4] + w3 * v[5];
    o.w = bias + w0 * v[3] + w1 * v[4] + w2 * v[5] + w3 * v[6];
    o.x = o.x / (1.f + __expf(-o.x));
    o.y = o.y / (1.f + __expf(-o.y));
    o.z = o.z / (1.f + __expf(-o.z));
    o.w = o.w / (1.f + __expf(-o.w));
    *(float4*)&uT[(size_t)d * BL + bl] = o;
}

// ---- fused chunk-decomposed selective scan (R10-proven 76.7 us version) ----
// One block per (b,d): 16 segments x 16 n-lanes = 256 threads.
// Phase A: local scan -> h_end, sum(delta) in LDS. Phase B: 16-thread serial
// combine -> h0. Phase C: re-scan with halving butterfly (lane n owns l0+n).
__global__ __launch_bounds__(256) void scan_fused(const float* __restrict__ deltaT,
        const float* __restrict__ uT, const float* __restrict__ xdbl,
        const float* __restrict__ xzT, const float* __restrict__ A_log,
        const float* __restrict__ Dp, float* __restrict__ yT)
{
    __shared__ float hend_s[G_][NS + 1];
    __shared__ float h0_s[G_][NS + 1];
    __shared__ float sdv_s[G_];

    const int tid = threadIdx.x;
    const int n = tid & 15;
    const int seg = tid >> 4;          // 0..15
    const int bd = blockIdx.x;         // b*DI + d
    const int d = bd & (DI - 1);
    const int b = bd >> 10;

    const float Acoef = -__expf(A_log[d * NS + n]);
    const float Dd = Dp[d];

    const size_t base_t = (size_t)d * BL + b * L_ + seg * SEG;
    const size_t base_z = (size_t)(DI + d) * BL + b * L_ + seg * SEG;
    const size_t base_x = (size_t)b * L_ * XDC + (size_t)seg * SEG * XDC;

    // ---- Phase A ----
    float h = 0.f, sdv = 0.f;
    for (int l0 = 0; l0 < SEG; l0 += 16) {
        float dv[16], uv[16], Bv[16];
        {
            const float4* dp = (const float4*)(deltaT + base_t + l0);
            const float4* up = (const float4*)(uT + base_t + l0);
            #pragma unroll
            for (int i = 0; i < 4; i++) {
                *(float4*)&dv[i * 4] = dp[i];
                *(float4*)&uv[i * 4] = up[i];
            }
        }
        {
            const float* xp = xdbl + base_x + (size_t)l0 * XDC + 32 + n;
            #pragma unroll
            for (int j = 0; j < 16; j++) Bv[j] = xp[j * XDC];
        }
        #pragma unroll
        for (int j = 0; j < 16; j++) {
            sdv += dv[j];
            Bv[j] *= dv[j] * uv[j];
            dv[j] = __expf(dv[j] * Acoef);
        }
        #pragma unroll
        for (int j = 0; j < 16; j++)
            h = fmaf(dv[j], h, Bv[j]);
    }
    hend_s[seg][n] = h;
    if (n == 0) sdv_s[seg] = sdv;
    __syncthreads();

    // ---- Phase B ----
    if (seg == 0) {
        float H = 0.f;
        #pragma unroll
        for (int s = 0; s < G_; s++) {
            h0_s[s][n] = H;
            H = hend_s[s][n] + __expf(Acoef * sdv_s[s]) * H;
        }
    }
    __syncthreads();

    // ---- Phase C ----
    h = h0_s[seg][n];
    for (int l0 = 0; l0 < SEG; l0 += 16) {
        float ug = uT [base_t + l0 + n];
        float zg = xzT[base_z + l0 + n];

        float dv[16], uv[16];
        {
            const float4* dp = (const float4*)(deltaT + base_t + l0);
            const float4* up = (const float4*)(uT + base_t + l0);
            #pragma unroll
            for (int i = 0; i < 4; i++) {
                *(float4*)&dv[i * 4] = dp[i];
                *(float4*)&uv[i * 4] = up[i];
            }
        }
        float Bv[16], Cv[16];
        {
            const float* xp = xdbl + base_x + (size_t)l0 * XDC + 32 + n;
            #pragma unroll
            for (int j = 0; j < 16; j++) {
                Bv[j] = xp[j * XDC];
                Cv[j] = xp[j * XDC + 16];
            }
        }
        #pragma unroll
        for (int j = 0; j < 16; j++) {
            Bv[j] *= dv[j] * uv[j];
            dv[j] = __expf(dv[j] * Acoef);
        }
        float p[16];
        #pragma unroll
        for (int j = 0; j < 16; j++) {
            h = fmaf(dv[j], h, Bv[j]);
            p[j] = h * Cv[j];
        }

        // halving butterfly: final owner of timestep j is lane n=j.
        float q8[8];
        #pragma unroll
        for (int k = 0; k < 8; k++) {
            float tt = (n & 8) ? p[k] : p[k + 8];
            float rr = __shfl_xor(tt, 8);
            q8[k] = ((n & 8) ? p[k + 8] : p[k]) + rr;
        }
        float q4[4];
        #pragma unroll
        for (int k = 0; k < 4; k++) {
            float tt = (n & 4) ? q8[k] : q8[k + 4];
            float rr = __shfl_xor(tt, 4);
            q4[k] = ((n & 4) ? q8[k + 4] : q8[k]) + rr;
        }
        float q2[2];
        #pragma unroll
        for (int k = 0; k < 2; k++) {
            float tt = (n & 2) ? q4[k] : q4[k + 2];
            float rr = __shfl_xor(tt, 2);
            q2[k] = ((n & 2) ? q4[k + 2] : q4[k]) + rr;
        }
        float tt = (n & 1) ? q2[0] : q2[1];
        float rr = __shfl_xor(tt, 1);
        float S = ((n & 1) ? q2[1] : q2[0]) + rr;

        float v = S + ug * Dd;
        v *= zg / (1.f + __expf(-zg));
        yT[base_t + l0 + n] = v;
    }
}

// yT fp32 [DI][BL] -> yB bf16 [BL][DI], 64x64 LDS tiles.
__global__ __launch_bounds__(256) void transpose_cast(const float* __restrict__ yT,
        ushort* __restrict__ yB)
{
    __shared__ float t[64][65];
    const int bl0 = blockIdx.x * 64, d0 = blockIdx.y * 64;
    const int tid = threadIdx.x;
    #pragma unroll
    for (int i = 0; i < 4; i++) {
        int chunk = tid + i * 256;
        int dr = chunk >> 4, c4 = (chunk & 15) * 4;
        const float4 v = *(const float4*)&yT[(size_t)(d0 + dr) * BL + bl0 + c4];
        t[dr][c4 + 0] = v.x; t[dr][c4 + 1] = v.y;
        t[dr][c4 + 2] = v.z; t[dr][c4 + 3] = v.w;
    }
    __syncthreads();
    #pragma unroll
    for (int i = 0; i < 4; i++) {
        int chunk = tid + i * 256;
        int br = chunk >> 4, dc4 = (chunk & 15) * 4;
        ushort4 o;
        o.x = f2bf(t[dc4 + 0][br]); o.y = f2bf(t[dc4 + 1][br]);
        o.z = f2bf(t[dc4 + 2][br]); o.w = f2bf(t[dc4 + 3][br]);
        *(ushort4*)&yB[(size_t)(bl0 + br) * DI + d0 + dc4] = o;
    }
}

// LayerNorm over last dim (512), one block per row, fp32 out.
__global__ __launch_bounds__(256) void ln_kernel(const float* __restrict__ r,
        const float* __restrict__ lnw, const float* __restrict__ lnb,
        float* __restrict__ out)
{
    int row = blockIdx.x;
    const float* rr = r + (size_t)row * DM;
    float v0 = rr[threadIdx.x], v1 = rr[threadIdx.x + 256];
    float s = v0 + v1, s2 = v0 * v0 + v1 * v1;
    #pragma unroll
    for (int off = 32; off > 0; off >>= 1) {
        s  += __shfl_down(s, off);
        s2 += __shfl_down(s2, off);
    }
    __shared__ float ls[4], ls2[4];
    __shared__ float mu_s, rstd_s;
    int wid = threadIdx.x >> 6, lane = threadIdx.x & 63;
    if (lane == 0) { ls[wid] = s; ls2[wid] = s2; }
    __syncthreads();
    if (threadIdx.x == 0) {
        float S = ls[0] + ls[1] + ls[2] + ls[3];
        float S2 = ls2[0] + ls2[1] + ls2[2] + ls2[3];
        float mu = S * (1.f / DM);
        float var = S2 * (1.f / DM) - mu * mu;
        mu_s = mu;
        rstd_s = rsqrtf(var + 1e-5f);
    }
    __syncthreads();
    float mu = mu_s, rstd = rstd_s;
    out[(size_t)row * DM + threadIdx.x] =
        (v0 - mu) * rstd * lnw[threadIdx.x] + lnb[threadIdx.x];
    out[(size_t)row * DM + threadIdx.x + 256] =
        (v1 - mu) * rstd * lnw[threadIdx.x + 256] + lnb[threadIdx.x + 256];
}

extern "C" void kernel_launch(void* const* d_in, const int* in_sizes, int n_in,
                              void* d_out, int out_size, void* d_ws, size_t ws_size,
                              hipStream_t stream)
{
    const float* x         = (const float*)d_in[0];
    const float* in_proj_w = (const float*)d_in[1];
    const float* conv_w    = (const float*)d_in[2];
    const float* conv_b    = (const float*)d_in[3];
    const float* x_proj_w  = (const float*)d_in[4];
    const float* dt_proj_w = (const float*)d_in[5];
    const float* dt_proj_b = (const float*)d_in[6];
    const float* A_log     = (const float*)d_in[7];
    const float* Dvec      = (const float*)d_in[8];
    const float* out_proj_w= (const float*)d_in[9];
    const float* ln_w      = (const float*)d_in[10];
    const float* ln_b      = (const float*)d_in[11];
    float* out = (float*)d_out;

    // fp32 regions (floats). Total ~90 MB.
    float* ws     = (float*)d_ws;
    float* xzT    = ws;                                  // 2048x4096 (32 MB)
    float* uT     = xzT    + (size_t)2048 * BL;          // 1024x4096 (16 MB)
    float* xdbl   = uT     + (size_t)DI * BL;            // 4096x64   (1 MB)
    float* deltaT = xdbl   + (size_t)BL * XDC;           // 1024x4096 (16 MB)
    float* yT     = deltaT + (size_t)DI * BL;            // 1024x4096 (16 MB)
    float* r      = yT     + (size_t)DI * BL;            // 4096x512  (8 MB)
    ushort* wOutB = (ushort*)(r + (size_t)BL * DM);      // 512x1024 bf16 (1 MB)
    // aliases over time-dead regions (strictly sequential reuse):
    ushort* xB    = (ushort*)yT;                          // x bf16 (4 MB), dead after gemm1
    float*  xdblp = yT;                                   // gemm3 partials (4 MB), after gemm1
    ushort* wInB  = (ushort*)deltaT;                      // in_proj bf16 (2 MB), dead before delta writes deltaT
    ushort* yB    = (ushort*)deltaT;                      // y bf16 (8 MB), written after scan (deltaT dead)

    dim3 blk(256);

    // 0) bf16 casts (x, in_proj_w, out_proj_w) in one launch
    cast_all<<<(917504 + 255) / 256, blk, 0, stream>>>(
        x, in_proj_w, out_proj_w, xB, wInB, wOutB);

    // 1) xzT[e][bl] = in_proj_w @ x^T : M=2048, N=4096, K=512 (MFMA)
    gemm_mfma<0><<<dim3(BL / 128, 2048 / 128), blk, 0, stream>>>(
        wInB, xB, xzT, DM, BL, nullptr);

    // 2) uT = silu(causal_conv(xsT) + cb)
    conv_silu<<<(DI * BL / 4) / 256, blk, 0, stream>>>(xzT, conv_w, conv_b, uT);

    // 3) x_dbl = u @ x_proj_w^T : split-K partials + reduce
    gemm3_splitk<<<dim3(KS, BL / 32), blk, 0, stream>>>(uT, x_proj_w, xdblp);
    gemm3_reduce<<<(BL * XDC / 4) / 256, blk, 0, stream>>>(xdblp, xdbl);

    // 4) deltaT = softplus(dt @ dtw^T + b) as SIMT dot kernel (K=32, fp32)
    delta_kernel<<<(DI / 4 * BL) / 256, blk, 0, stream>>>(
        xdbl, dt_proj_w, dt_proj_b, deltaT);

    // 5) fused selective scan + gate (one block per (b,d))
    scan_fused<<<B_ * DI, blk, 0, stream>>>(
        deltaT, uT, xdbl, xzT, A_log, Dvec, yT);

    // 6a) yT -> yB (bf16, [bl][d])
    transpose_cast<<<dim3(BL / 64, DI / 64), blk, 0, stream>>>(yT, yB);

    // 6b) r[bl][dm] = y @ out_proj_w^T + x : M=4096, N=512, K=1024 (MFMA, resid epi)
    gemm_mfma<2><<<dim3(DM / 128, BL / 128), blk, 0, stream>>>(
        yB, wOutB, r, DI, DM, x);

    // 7) LayerNorm -> fp32 out
    ln_kernel<<<BL, blk, 0, stream>>>(r, ln_w, ln_b, out);
}